// Round 1
// baseline (345.804 us; speedup 1.0000x reference)
//
#include <hip/hip_runtime.h>

#define N_FEAT 128
#define N_CLS 64

// 1) degree histogram over dst
__global__ void k_deg(const int* __restrict__ dst, int ne, int* __restrict__ deg) {
    int i = blockIdx.x * blockDim.x + threadIdx.x;
    if (i < ne) atomicAdd(&deg[dst[i]], 1);
}

// 2) single-block exclusive scan of deg -> off, copy to cursor, fused norm = rsqrt(max(deg,1))
__global__ __launch_bounds__(1024) void k_scan(const int* __restrict__ deg, int n,
                                               int* __restrict__ off, int* __restrict__ cur,
                                               float* __restrict__ nrm) {
    __shared__ int sums[1024];
    int t = threadIdx.x;
    int chunk = (n + 1023) >> 10;
    int s = t * chunk;
    int e = min(s + chunk, n);
    int local = 0;
    for (int i = s; i < e; ++i) local += deg[i];
    sums[t] = local;
    __syncthreads();
    // Hillis-Steele inclusive scan over 1024 partial sums
    for (int d = 1; d < 1024; d <<= 1) {
        int v = (t >= d) ? sums[t - d] : 0;
        __syncthreads();
        sums[t] += v;
        __syncthreads();
    }
    int run = (t > 0) ? sums[t - 1] : 0;
    for (int i = s; i < e; ++i) {
        off[i] = run;
        cur[i] = run;
        run += deg[i];
        nrm[i] = rsqrtf(fmaxf((float)deg[i], 1.0f));
    }
    if (t == 0) off[n] = sums[1023];
}

// 3) counting-sort fill: esrc[off[dst]..off[dst]+deg) = src ids of edges into dst
__global__ void k_fill(const int* __restrict__ src, const int* __restrict__ dst, int ne,
                       int* __restrict__ cur, int* __restrict__ esrc) {
    int i = blockIdx.x * blockDim.x + threadIdx.x;
    if (i < ne) {
        int d = dst[i];
        int p = atomicAdd(&cur[d], 1);
        esrc[p] = src[i];
    }
}

// 4) Y[node] = (X[node] * nrm[node]) @ W   -- thread-per-node, 64 fp32 accumulators
__global__ __launch_bounds__(256) void k_gemm(const float* __restrict__ X,
                                              const float* __restrict__ W,
                                              const float* __restrict__ nrm,
                                              float* __restrict__ Y, int n) {
    int node = blockIdx.x * 256 + threadIdx.x;
    if (node >= n) return;
    float acc[N_CLS];
#pragma unroll
    for (int c = 0; c < N_CLS; ++c) acc[c] = 0.f;
    const float* xrow = X + (size_t)node * N_FEAT;
    for (int k4 = 0; k4 < N_FEAT; k4 += 4) {
        float4 xv = *(const float4*)(xrow + k4);
        float xs0 = xv.x, xs1 = xv.y, xs2 = xv.z, xs3 = xv.w;
#pragma unroll
        for (int j = 0; j < 4; ++j) {
            float xj = (j == 0) ? xs0 : (j == 1) ? xs1 : (j == 2) ? xs2 : xs3;
            const float* wrow = W + (size_t)(k4 + j) * N_CLS;
#pragma unroll
            for (int c = 0; c < N_CLS; c += 4) {
                float4 wv = *(const float4*)(wrow + c);
                acc[c + 0] = fmaf(xj, wv.x, acc[c + 0]);
                acc[c + 1] = fmaf(xj, wv.y, acc[c + 1]);
                acc[c + 2] = fmaf(xj, wv.z, acc[c + 2]);
                acc[c + 3] = fmaf(xj, wv.w, acc[c + 3]);
            }
        }
    }
    float nv = nrm[node];
    float* yrow = Y + (size_t)node * N_CLS;
#pragma unroll
    for (int c = 0; c < N_CLS; c += 4) {
        float4 o;
        o.x = acc[c + 0] * nv;
        o.y = acc[c + 1] * nv;
        o.z = acc[c + 2] * nv;
        o.w = acc[c + 3] * nv;
        *(float4*)(yrow + c) = o;
    }
}

// 5) wave-per-dst-node gather: out[n][c] = nrm[n] * sum_{e into n} Y[esrc[e]][c] + b[c]
__global__ __launch_bounds__(256) void k_agg(const int* __restrict__ off,
                                             const int* __restrict__ esrc,
                                             const float* __restrict__ Y,
                                             const float* __restrict__ nrm,
                                             const float* __restrict__ b,
                                             float* __restrict__ out, int n) {
    int wid = (int)((blockIdx.x * (size_t)blockDim.x + threadIdx.x) >> 6);
    int lane = threadIdx.x & 63;
    if (wid >= n) return;
    int s = off[wid];
    int e = off[wid + 1];
    float acc = 0.f;
    for (int p = s; p < e; ++p) {
        int sn = esrc[p];  // uniform per wave -> scalar load
        acc += Y[(size_t)sn * N_CLS + lane];  // coalesced 256B row read
    }
    out[(size_t)wid * N_CLS + lane] = acc * nrm[wid] + b[lane];
}

extern "C" void kernel_launch(void* const* d_in, const int* in_sizes, int n_in,
                              void* d_out, int out_size, void* d_ws, size_t ws_size,
                              hipStream_t stream) {
    const float* X = (const float*)d_in[0];
    const float* W = (const float*)d_in[1];
    const float* b = (const float*)d_in[2];
    const int* src = (const int*)d_in[3];
    const int* dst = (const int*)d_in[4];
    int n = in_sizes[0] / N_FEAT;
    int ne = in_sizes[3];
    float* out = (float*)d_out;

    char* w = (char*)d_ws;
    auto take = [&](size_t bytes) {
        char* p = w;
        w += (bytes + 255) & ~(size_t)255;
        return p;
    };
    int* deg = (int*)take((size_t)n * 4);
    int* off = (int*)take((size_t)(n + 1) * 4);
    int* cur = (int*)take((size_t)n * 4);
    int* esrc = (int*)take((size_t)ne * 4);
    float* nrm = (float*)take((size_t)n * 4);
    float* Y = (float*)take((size_t)n * N_CLS * 4);

    hipMemsetAsync(deg, 0, (size_t)n * 4, stream);

    const int tb = 256;
    k_deg<<<(ne + tb - 1) / tb, tb, 0, stream>>>(dst, ne, deg);
    k_scan<<<1, 1024, 0, stream>>>(deg, n, off, cur, nrm);
    k_fill<<<(ne + tb - 1) / tb, tb, 0, stream>>>(src, dst, ne, cur, esrc);
    k_gemm<<<(n + tb - 1) / tb, tb, 0, stream>>>(X, W, nrm, Y, n);
    long long total_threads = (long long)n * 64;
    k_agg<<<(int)((total_threads + tb - 1) / tb), tb, 0, stream>>>(off, esrc, Y, nrm, b, out, n);
}

// Round 2
// 225.565 us; speedup vs baseline: 1.5331x; 1.5331x over previous
//
#include <hip/hip_runtime.h>

#define N_FEAT 128
#define N_CLS 64

// 1) degree histogram over dst
__global__ void k_deg(const int* __restrict__ dst, int ne, int* __restrict__ deg) {
    int i = blockIdx.x * blockDim.x + threadIdx.x;
    if (i < ne) atomicAdd(&deg[dst[i]], 1);
}

// 2a) per-block exclusive scan of deg (256 elems/block), emit block sums
__global__ __launch_bounds__(256) void k_scan1(const int* __restrict__ deg, int n,
                                               int* __restrict__ offtmp, int* __restrict__ bsum) {
    __shared__ int s[256];
    int t = threadIdx.x;
    int i = blockIdx.x * 256 + t;
    int v = (i < n) ? deg[i] : 0;
    s[t] = v;
    __syncthreads();
    for (int d = 1; d < 256; d <<= 1) {
        int u = (t >= d) ? s[t - d] : 0;
        __syncthreads();
        s[t] += u;
        __syncthreads();
    }
    if (i < n) offtmp[i] = s[t] - v;  // exclusive
    if (t == 255) bsum[blockIdx.x] = s[255];
}

// 2b) single tiny block: exclusive scan of block sums (nb <= 1024)
__global__ __launch_bounds__(1024) void k_scan2(int* __restrict__ bsum, int nb) {
    __shared__ int s[1024];
    int t = threadIdx.x;
    int v = (t < nb) ? bsum[t] : 0;
    s[t] = v;
    __syncthreads();
    for (int d = 1; d < 1024; d <<= 1) {
        int u = (t >= d) ? s[t - d] : 0;
        __syncthreads();
        s[t] += u;
        __syncthreads();
    }
    if (t < nb) bsum[t] = s[t] - v;  // exclusive
}

// 2c) finalize: off = offtmp + block offset; cur = off; nrm = rsqrt(max(deg,1))
__global__ __launch_bounds__(256) void k_scan3(const int* __restrict__ deg,
                                               const int* __restrict__ offtmp,
                                               const int* __restrict__ bsum, int n, int ne,
                                               int* __restrict__ off, int* __restrict__ cur,
                                               float* __restrict__ nrm) {
    int i = blockIdx.x * 256 + threadIdx.x;
    if (i < n) {
        int o = offtmp[i] + bsum[blockIdx.x];
        off[i] = o;
        cur[i] = o;
        nrm[i] = rsqrtf(fmaxf((float)deg[i], 1.0f));
    }
    if (i == 0) off[n] = ne;  // total edge count is known
}

// 3) counting-sort fill: esrc[off[dst]..off[dst]+deg) = src ids of edges into dst
__global__ void k_fill(const int* __restrict__ src, const int* __restrict__ dst, int ne,
                       int* __restrict__ cur, int* __restrict__ esrc) {
    int i = blockIdx.x * blockDim.x + threadIdx.x;
    if (i < ne) {
        int d = dst[i];
        int p = atomicAdd(&cur[d], 1);
        esrc[p] = src[i];
    }
}

// 4) Y[node] = (X[node] * nrm[node]) @ W   -- thread-per-node, 64 fp32 accumulators
__global__ __launch_bounds__(256) void k_gemm(const float* __restrict__ X,
                                              const float* __restrict__ W,
                                              const float* __restrict__ nrm,
                                              float* __restrict__ Y, int n) {
    int node = blockIdx.x * 256 + threadIdx.x;
    if (node >= n) return;
    float acc[N_CLS];
#pragma unroll
    for (int c = 0; c < N_CLS; ++c) acc[c] = 0.f;
    const float* xrow = X + (size_t)node * N_FEAT;
    for (int k4 = 0; k4 < N_FEAT; k4 += 4) {
        float4 xv = *(const float4*)(xrow + k4);
        float xs0 = xv.x, xs1 = xv.y, xs2 = xv.z, xs3 = xv.w;
#pragma unroll
        for (int j = 0; j < 4; ++j) {
            float xj = (j == 0) ? xs0 : (j == 1) ? xs1 : (j == 2) ? xs2 : xs3;
            const float* wrow = W + (size_t)(k4 + j) * N_CLS;
#pragma unroll
            for (int c = 0; c < N_CLS; c += 4) {
                float4 wv = *(const float4*)(wrow + c);
                acc[c + 0] = fmaf(xj, wv.x, acc[c + 0]);
                acc[c + 1] = fmaf(xj, wv.y, acc[c + 1]);
                acc[c + 2] = fmaf(xj, wv.z, acc[c + 2]);
                acc[c + 3] = fmaf(xj, wv.w, acc[c + 3]);
            }
        }
    }
    float nv = nrm[node];
    float* yrow = Y + (size_t)node * N_CLS;
#pragma unroll
    for (int c = 0; c < N_CLS; c += 4) {
        float4 o;
        o.x = acc[c + 0] * nv;
        o.y = acc[c + 1] * nv;
        o.z = acc[c + 2] * nv;
        o.w = acc[c + 3] * nv;
        *(float4*)(yrow + c) = o;
    }
}

// 5) wave-per-dst-node gather: out[n][c] = nrm[n] * sum_{e into n} Y[esrc[e]][c] + b[c]
__global__ __launch_bounds__(256) void k_agg(const int* __restrict__ off,
                                             const int* __restrict__ esrc,
                                             const float* __restrict__ Y,
                                             const float* __restrict__ nrm,
                                             const float* __restrict__ b,
                                             float* __restrict__ out, int n) {
    int wid = (int)((blockIdx.x * (size_t)blockDim.x + threadIdx.x) >> 6);
    int lane = threadIdx.x & 63;
    if (wid >= n) return;
    int s = off[wid];
    int e = off[wid + 1];
    float acc = 0.f;
    for (int p = s; p < e; ++p) {
        int sn = esrc[p];  // uniform per wave -> scalar load
        acc += Y[(size_t)sn * N_CLS + lane];  // coalesced 256B row read
    }
    out[(size_t)wid * N_CLS + lane] = acc * nrm[wid] + b[lane];
}

extern "C" void kernel_launch(void* const* d_in, const int* in_sizes, int n_in,
                              void* d_out, int out_size, void* d_ws, size_t ws_size,
                              hipStream_t stream) {
    const float* X = (const float*)d_in[0];
    const float* W = (const float*)d_in[1];
    const float* b = (const float*)d_in[2];
    const int* src = (const int*)d_in[3];
    const int* dst = (const int*)d_in[4];
    int n = in_sizes[0] / N_FEAT;
    int ne = in_sizes[3];
    float* out = (float*)d_out;

    char* w = (char*)d_ws;
    auto take = [&](size_t bytes) {
        char* p = w;
        w += (bytes + 255) & ~(size_t)255;
        return p;
    };
    int nb = (n + 255) / 256;
    int* deg = (int*)take((size_t)n * 4);
    int* off = (int*)take((size_t)(n + 1) * 4);
    int* cur = (int*)take((size_t)n * 4);
    int* offtmp = (int*)take((size_t)n * 4);
    int* bsum = (int*)take((size_t)nb * 4);
    int* esrc = (int*)take((size_t)ne * 4);
    float* nrm = (float*)take((size_t)n * 4);
    float* Y = (float*)take((size_t)n * N_CLS * 4);

    hipMemsetAsync(deg, 0, (size_t)n * 4, stream);

    const int tb = 256;
    k_deg<<<(ne + tb - 1) / tb, tb, 0, stream>>>(dst, ne, deg);
    k_scan1<<<nb, 256, 0, stream>>>(deg, n, offtmp, bsum);
    k_scan2<<<1, 1024, 0, stream>>>(bsum, nb);
    k_scan3<<<nb, 256, 0, stream>>>(deg, offtmp, bsum, n, ne, off, cur, nrm);
    k_fill<<<(ne + tb - 1) / tb, tb, 0, stream>>>(src, dst, ne, cur, esrc);
    k_gemm<<<(n + tb - 1) / tb, tb, 0, stream>>>(X, W, nrm, Y, n);
    long long total_threads = (long long)n * 64;
    k_agg<<<(int)((total_threads + tb - 1) / tb), tb, 0, stream>>>(off, esrc, Y, nrm, b, out, n);
}

// Round 3
// 175.739 us; speedup vs baseline: 1.9677x; 1.2835x over previous
//
#include <hip/hip_runtime.h>

#define N_FEAT 128
#define N_CLS 64

// 1) degree histogram over dst
__global__ __launch_bounds__(256) void k_deg(const int* __restrict__ dst, int ne,
                                             int* __restrict__ deg) {
    int i = blockIdx.x * blockDim.x + threadIdx.x;
    if (i < ne) atomicAdd(&deg[dst[i]], 1);
}

// 2a) per-block exclusive scan of deg (256 elems/block), emit block sums
__global__ __launch_bounds__(256) void k_scan1(const int* __restrict__ deg, int n,
                                               int* __restrict__ offtmp, int* __restrict__ bsum) {
    __shared__ int s[256];
    int t = threadIdx.x;
    int i = blockIdx.x * 256 + t;
    int v = (i < n) ? deg[i] : 0;
    s[t] = v;
    __syncthreads();
    for (int d = 1; d < 256; d <<= 1) {
        int u = (t >= d) ? s[t - d] : 0;
        __syncthreads();
        s[t] += u;
        __syncthreads();
    }
    if (i < n) offtmp[i] = s[t] - v;  // exclusive
    if (t == 255) bsum[blockIdx.x] = s[255];
}

// 2b) single tiny block: exclusive scan of block sums (nb <= 1024)
__global__ __launch_bounds__(1024) void k_scan2(int* __restrict__ bsum, int nb) {
    __shared__ int s[1024];
    int t = threadIdx.x;
    int v = (t < nb) ? bsum[t] : 0;
    s[t] = v;
    __syncthreads();
    for (int d = 1; d < 1024; d <<= 1) {
        int u = (t >= d) ? s[t - d] : 0;
        __syncthreads();
        s[t] += u;
        __syncthreads();
    }
    if (t < nb) bsum[t] = s[t] - v;  // exclusive
}

// 2c) finalize: off = offtmp + block offset; cur = off; nrm = rsqrt(max(deg,1))
__global__ __launch_bounds__(256) void k_scan3(const int* __restrict__ deg,
                                               const int* __restrict__ offtmp,
                                               const int* __restrict__ bsum, int n, int ne,
                                               int* __restrict__ off, int* __restrict__ cur,
                                               float* __restrict__ nrm) {
    int i = blockIdx.x * 256 + threadIdx.x;
    if (i < n) {
        int o = offtmp[i] + bsum[blockIdx.x];
        off[i] = o;
        cur[i] = o;
        nrm[i] = rsqrtf(fmaxf((float)deg[i], 1.0f));
    }
    if (i == 0) off[n] = ne;  // total edge count is known
}

// 3) counting-sort fill: esrc[off[dst]..off[dst]+deg) = src ids of edges into dst
__global__ __launch_bounds__(256) void k_fill(const int* __restrict__ src,
                                              const int* __restrict__ dst, int ne,
                                              int* __restrict__ cur, int* __restrict__ esrc) {
    int i = blockIdx.x * blockDim.x + threadIdx.x;
    if (i < ne) {
        int d = dst[i];
        int p = atomicAdd(&cur[d], 1);
        esrc[p] = src[i];
    }
}

// 4) Y[node] = (X[node] * nrm[node]) @ W   -- thread-per-node, 64 fp32 accumulators
__global__ __launch_bounds__(256) void k_gemm(const float* __restrict__ X,
                                              const float* __restrict__ W,
                                              const float* __restrict__ nrm,
                                              float* __restrict__ Y, int n) {
    int node = blockIdx.x * 256 + threadIdx.x;
    if (node >= n) return;
    float acc[N_CLS];
#pragma unroll
    for (int c = 0; c < N_CLS; ++c) acc[c] = 0.f;
    const float* xrow = X + (size_t)node * N_FEAT;
    for (int k4 = 0; k4 < N_FEAT; k4 += 4) {
        float4 xv = *(const float4*)(xrow + k4);
        float xs0 = xv.x, xs1 = xv.y, xs2 = xv.z, xs3 = xv.w;
#pragma unroll
        for (int j = 0; j < 4; ++j) {
            float xj = (j == 0) ? xs0 : (j == 1) ? xs1 : (j == 2) ? xs2 : xs3;
            const float* wrow = W + (size_t)(k4 + j) * N_CLS;
#pragma unroll
            for (int c = 0; c < N_CLS; c += 4) {
                float4 wv = *(const float4*)(wrow + c);
                acc[c + 0] = fmaf(xj, wv.x, acc[c + 0]);
                acc[c + 1] = fmaf(xj, wv.y, acc[c + 1]);
                acc[c + 2] = fmaf(xj, wv.z, acc[c + 2]);
                acc[c + 3] = fmaf(xj, wv.w, acc[c + 3]);
            }
        }
    }
    float nv = nrm[node];
    float* yrow = Y + (size_t)node * N_CLS;
#pragma unroll
    for (int c = 0; c < N_CLS; c += 4) {
        float4 o;
        o.x = acc[c + 0] * nv;
        o.y = acc[c + 1] * nv;
        o.z = acc[c + 2] * nv;
        o.w = acc[c + 3] * nv;
        *(float4*)(yrow + c) = o;
    }
}

// 5) wave-per-dst-node gather, 4 edge-slots x 16 lanes, float4/lane, unroll x2:
//    out[n][c] = nrm[n] * sum_{e into n} Y[esrc[e]][c] + b[c]
__global__ __launch_bounds__(256) void k_agg(const int* __restrict__ off,
                                             const int* __restrict__ esrc,
                                             const float* __restrict__ Y,
                                             const float* __restrict__ nrm,
                                             const float* __restrict__ b,
                                             float* __restrict__ out, int n) {
    int wid = (int)((blockIdx.x * (size_t)blockDim.x + threadIdx.x) >> 6);
    if (wid >= n) return;
    int lane = threadIdx.x & 63;
    int g = lane >> 4;        // edge slot 0..3
    int c = (lane & 15) * 4;  // column base (16 lanes x float4 = full 64-col row)
    int s = off[wid];
    int e = off[wid + 1];
    float4 a0 = make_float4(0.f, 0.f, 0.f, 0.f);
    float4 a1 = make_float4(0.f, 0.f, 0.f, 0.f);
    int p = s + g;
    for (; p + 4 < e; p += 8) {
        int s0 = esrc[p];
        int s1 = esrc[p + 4];
        float4 r0 = *(const float4*)(Y + (size_t)s0 * N_CLS + c);
        float4 r1 = *(const float4*)(Y + (size_t)s1 * N_CLS + c);
        a0.x += r0.x; a0.y += r0.y; a0.z += r0.z; a0.w += r0.w;
        a1.x += r1.x; a1.y += r1.y; a1.z += r1.z; a1.w += r1.w;
    }
    if (p < e) {
        int s0 = esrc[p];
        float4 r0 = *(const float4*)(Y + (size_t)s0 * N_CLS + c);
        a0.x += r0.x; a0.y += r0.y; a0.z += r0.z; a0.w += r0.w;
    }
    a0.x += a1.x; a0.y += a1.y; a0.z += a1.z; a0.w += a1.w;
    // reduce the 4 edge-slot partials: xor by 16 then 32
#pragma unroll
    for (int m = 16; m <= 32; m <<= 1) {
        a0.x += __shfl_xor(a0.x, m);
        a0.y += __shfl_xor(a0.y, m);
        a0.z += __shfl_xor(a0.z, m);
        a0.w += __shfl_xor(a0.w, m);
    }
    if (lane < 16) {
        float nv = nrm[wid];
        float4 bv = *(const float4*)(b + c);
        float4 o;
        o.x = a0.x * nv + bv.x;
        o.y = a0.y * nv + bv.y;
        o.z = a0.z * nv + bv.z;
        o.w = a0.w * nv + bv.w;
        *(float4*)(out + (size_t)wid * N_CLS + c) = o;
    }
}

extern "C" void kernel_launch(void* const* d_in, const int* in_sizes, int n_in,
                              void* d_out, int out_size, void* d_ws, size_t ws_size,
                              hipStream_t stream) {
    const float* X = (const float*)d_in[0];
    const float* W = (const float*)d_in[1];
    const float* b = (const float*)d_in[2];
    const int* src = (const int*)d_in[3];
    const int* dst = (const int*)d_in[4];
    int n = in_sizes[0] / N_FEAT;
    int ne = in_sizes[3];
    float* out = (float*)d_out;

    char* w = (char*)d_ws;
    auto take = [&](size_t bytes) {
        char* p = w;
        w += (bytes + 255) & ~(size_t)255;
        return p;
    };
    int nb = (n + 255) / 256;
    int* deg = (int*)take((size_t)n * 4);
    int* off = (int*)take((size_t)(n + 1) * 4);
    int* cur = (int*)take((size_t)n * 4);
    int* offtmp = (int*)take((size_t)n * 4);
    int* bsum = (int*)take((size_t)nb * 4);
    int* esrc = (int*)take((size_t)ne * 4);
    float* nrm = (float*)take((size_t)n * 4);
    float* Y = (float*)take((size_t)n * N_CLS * 4);

    hipMemsetAsync(deg, 0, (size_t)n * 4, stream);

    const int tb = 256;
    k_deg<<<(ne + tb - 1) / tb, tb, 0, stream>>>(dst, ne, deg);
    k_scan1<<<nb, 256, 0, stream>>>(deg, n, offtmp, bsum);
    k_scan2<<<1, 1024, 0, stream>>>(bsum, nb);
    k_scan3<<<nb, 256, 0, stream>>>(deg, offtmp, bsum, n, ne, off, cur, nrm);
    k_fill<<<(ne + tb - 1) / tb, tb, 0, stream>>>(src, dst, ne, cur, esrc);
    k_gemm<<<(n + tb - 1) / tb, tb, 0, stream>>>(X, W, nrm, Y, n);
    long long total_threads = (long long)n * 64;
    k_agg<<<(int)((total_threads + tb - 1) / tb), tb, 0, stream>>>(off, esrc, Y, nrm, b, out, n);
}